// Round 22
// baseline (839.385 us; speedup 1.0000x reference)
//
#include <hip/hip_runtime.h>
#include <hip/hip_bf16.h>

#define Dd 64
#define Hh 128
#define Ww 128
#define Cc 32

// block tile: 32d x 16h x 16w outputs; 512 threads = 8 waves.
// wave = (dgrp 0..3) x (whv 0..1). r20 kernel with __launch_bounds__(512,6):
// 3 blocks/CU = 6 waves/SIMD needs <=85 regs/wave; r20 allocated ~88 at the
// declared 4 waves/EU, which is why occupancy pinned at 2 blocks (42%).
#define BD 32
#define BH 16
#define BW 16
#define ZR (BD + 6)        // 38 staged z-planes
#define HR (BH + 6)        // 22 staged h-rows
#define NR (ZR * HR)       // 836 rows
#define RCOLS 24           // bf16 cols per row; col = w - w0 + 4 (left halo 4)
#define BLKROW 3
#define NBLK (NR * BLKROW) // 2508 16B blocks to stage

// A-table, b64 half-window entries: E(pl,s) = 4 taps [wt[s+j-7], j=0..3].
// fragment(pl,a) = (E(pl,a), E(pl,a+4)) — two ds_read_b64, +32B imm offset.
// 1016 entries x 8B = 8128 B. Total LDS 40128+8128 = 48256.
// Dead ends (measured): r12 global wtab = L2 storm; r13 rotation = worse
// banks; r15/16 incremental staging = serialized loads; r15 inline-asm MFMA
// = sched fence; r17 full unroll = spill; r21 BD=16 = +16% staging work.
#define E7 18
#define E3N 14
#define W3B (49 * E7)            // 882
#define ZE  (W3B + 9 * E3N)      // 1008 (zero region 1008..1015)
#define NEnt (ZE + 8)            // 1016

typedef __attribute__((ext_vector_type(8))) short short8;   // 8 bf16 (4 VGPR)
typedef __attribute__((ext_vector_type(4))) float floatx4;  // MFMA acc

static __device__ __forceinline__ unsigned short f2bf(float f) {
    unsigned u = __builtin_bit_cast(unsigned, f);
    u += 0x7fffu + ((u >> 16) & 1u);   // RNE
    return (unsigned short)(u >> 16);
}

static __device__ __forceinline__ unsigned pk2(float a, float b) {
    union { __hip_bfloat162 h; unsigned u; } cv;
    cv.h = __float22bfloat162_rn(make_float2(a, b));   // v_cvt_pk_bf16_f32
    return cv.u;
}

// fragment = two aligned b64 reads at entry idx and idx+4 (same base, +32B)
static __device__ __forceinline__ short8 ldfrag(const unsigned short* wt, int idx) {
    uint2 lo = *(const uint2*)&wt[idx * 4];
    uint2 hi = *(const uint2*)&wt[idx * 4 + 16];
    union { unsigned u[4]; short8 s; } cv;
    cv.u[0] = lo.x; cv.u[1] = lo.y; cv.u[2] = hi.x; cv.u[3] = hi.y;
    return cv.s;
}

__global__ __launch_bounds__(512, 6) void replk_mfma(
    const float* __restrict__ x,
    const float* __restrict__ w7, const float* __restrict__ w3, const float* __restrict__ w1,
    const float* __restrict__ g7, const float* __restrict__ b7, const float* __restrict__ m7, const float* __restrict__ v7,
    const float* __restrict__ g3, const float* __restrict__ b3, const float* __restrict__ m3, const float* __restrict__ v3,
    const float* __restrict__ g1, const float* __restrict__ b1, const float* __restrict__ m1, const float* __restrict__ v1,
    float* __restrict__ out)
{
    __shared__ __align__(16) unsigned short tile[NR * RCOLS];  // 40128 B
    __shared__ __align__(16) unsigned short wtab[NEnt * 4];    // 8128 B

    const int tid = threadIdx.x;

    // XCD-aware swizzle: 8192 blocks, 8 XCDs, 1024 contiguous per XCD.
    const unsigned lid = blockIdx.x;
    const unsigned nl = (lid & 7u) * 1024u + (lid >> 3);
    const int bx = nl & 127;
    const int slab = nl >> 7;
    const int c = slab & 31;
    const int nb = slab >> 5;
    const int w0 = (bx & 7) * BW;
    const int h0 = ((bx >> 3) & 7) * BH;
    const int d0 = (bx >> 6) * BD;

    const float* xc = x + (size_t)(nb * Cc + c) * (Dd * Hh * Ww);

    // ---- build A half-window table (b64 entries) ----
    for (int e = tid; e < NEnt; e += 512) {
        unsigned short h4[4];
#pragma unroll
        for (int j = 0; j < 4; j++) {
            float v = 0.f;
            if (e < W3B) {
                int pl = e / E7, s = e - pl * E7;
                int t = s + j - 7;
                if ((unsigned)t < 7u)
                    v = w7[c * 343 + (pl / 7) * 49 + (pl % 7) * 7 + t];
            } else if (e < ZE) {
                int e2 = e - W3B;
                int p3 = e2 / E3N, s = e2 - p3 * E3N;
                int t = s + j - 7;
                if ((unsigned)t < 3u)
                    v = w3[c * 27 + (p3 / 3) * 9 + (p3 % 3) * 3 + t];
            }
            h4[j] = f2bf(v);
        }
        uint2 pk;
        pk.x = (unsigned)h4[0] | ((unsigned)h4[1] << 16);
        pk.y = (unsigned)h4[2] | ((unsigned)h4[3] << 16);
        *(uint2*)&wtab[e * 4] = pk;
    }

    // ---- stage input tile fp32 -> bf16 (cvt_pk), division-based indices ----
    // (divisions keep the 5 iterations' addresses INDEPENDENT so all loads
    //  issue up front — incremental chains serialize them)
#pragma unroll
    for (int it = 0; it < 5; it++) {
        int s = tid + it * 512;
        if (s < NBLK) {
            int R = s / BLKROW, bl = s - R * BLKROW;
            int zi = R / HR, hr = R - zi * HR;
            int gz = d0 - 3 + zi, gh = h0 - 3 + hr, gw0 = w0 - 4 + bl * 8;
            float v[8];
#pragma unroll
            for (int j = 0; j < 8; j++) v[j] = 0.f;
            if ((unsigned)gz < (unsigned)Dd && (unsigned)gh < (unsigned)Hh) {
                const float* src = xc + ((size_t)gz * Hh + gh) * Ww + gw0;
                if (gw0 >= 0 && gw0 + 8 <= Ww) {
                    float4 a = *(const float4*)src;
                    float4 b = *(const float4*)(src + 4);
                    v[0] = a.x; v[1] = a.y; v[2] = a.z; v[3] = a.w;
                    v[4] = b.x; v[5] = b.y; v[6] = b.z; v[7] = b.w;
                } else {
#pragma unroll
                    for (int j = 0; j < 8; j++) {
                        int gw = gw0 + j;
                        if ((unsigned)gw < (unsigned)Ww) v[j] = src[j];
                    }
                }
            }
            uint4 pk;
            pk.x = pk2(v[0], v[1]);
            pk.y = pk2(v[2], v[3]);
            pk.z = pk2(v[4], v[5]);
            pk.w = pk2(v[6], v[7]);
            *(uint4*)&tile[R * RCOLS + bl * 8] = pk;
        }
    }

    // BN constants (wave-uniform)
    const float eps = 1e-5f;
    const float iv7 = g7[c] / sqrtf(v7[c] + eps);
    const float bb7 = b7[c] - m7[c] * iv7;
    const float iv3 = g3[c] / sqrtf(v3[c] + eps);
    const float bb3 = b3[c] - m3[c] * iv3;
    const float iv1 = g1[c] / sqrtf(v1[c] + eps);
    const float bb1 = b1[c] - m1[c] * iv1;
    const float s1 = w1[c] * iv1;

    __syncthreads();

    const int lane = tid & 63;
    const int wave = tid >> 6;        // 0..7
    const int whv = wave & 1;         // which 8-wide w half this wave owns
    const int dgrp = wave >> 1;       // which 8-d group
    const int q = lane & 15;          // m (A) / n (B,C,D)
    const int p = lane >> 4;
    const int khp = p >> 1;           // kh within pair
    const int kb  = p & 1;            // wc 16B-block
    const int ddl = q >> 3;           // d within M-pair (A side)
    const int mwq = q & 7;            // w within M (A side)
    const int zbase = dgrp * 8;       // wave's d-outputs [zbase, zbase+8)

    const int a7 = 8 * kb - mwq + 6;  // 7^3 window (valid [0,14))
    const int a3 = a7 - 2;            // 3^3 window (valid [0,10))

    floatx4 acc7[4], acc3[4];
#pragma unroll
    for (int i = 0; i < 4; i++) { acc7[i] = (floatx4)0.f; acc3[i] = (floatx4)0.f; }

    // ---- khg-outer loop: kh-pairs {0,1}{2,3}{4,5}{6,-}; 3^3 shares B of khg 1,2;
    //      each wave computes only its whv column half (B = 1 short8/zi) ----
#pragma unroll 1
    for (int khg = 0; khg < 4; khg++) {
        const int kh = 2 * khg + khp;                       // 0..7 (7 = zero)
        const bool ok7 = ((unsigned)a7 < 14u) && (kh <= 6);
        const int cb7 = ok7 ? (kh * E7 + a7 - ddl * 126) : (int)ZE;
        const int st7 = ok7 ? 126 : 0;
        short8 A7g[8];
#pragma unroll
        for (int rz = 0; rz < 8; rz++) {
            int idx = cb7 + rz * st7;
            if (rz == 0) idx = (ddl == 0 && ok7) ? idx : (int)ZE;  // kd=-1 lanes
            if (rz == 7) idx = (ddl == 1 && ok7) ? idx : (int)ZE;  // kd=7 lanes
            A7g[rz] = ldfrag(wtab, idx);
        }

        const bool has3 = (khg == 1) || (khg == 2);
        short8 A3g[4] = {};
        if (has3) {
            const int kh3 = 2 * (khg - 1) + khp;            // 0..3 (3 = zero)
            const bool ok3 = ((unsigned)a3 < 10u) && (kh3 <= 2);
            const int cb3 = ok3 ? (W3B + kh3 * E3N + a3 - ddl * 42) : (int)ZE;
            const int st3 = ok3 ? 42 : 0;
#pragma unroll
            for (int rz = 0; rz < 4; rz++) {
                int idx = cb3 + rz * st3;
                if (rz == 0) idx = (ddl == 0 && ok3) ? idx : (int)ZE;
                if (rz == 3) idx = (ddl == 1 && ok3) ? idx : (int)ZE;
                A3g[rz] = ldfrag(wtab, idx);
            }
        }

        // kh=7 lanes (khg=3, khp=1) have zero A: clamp their B row to kh=6's.
        const int rowadd = (khg == 3) ? 6 : (2 * khg + khp);

#pragma unroll
        for (int zi = 0; zi < 14; zi++) {
            const int R = (zbase + zi) * HR + q + rowadd;
            short8 B = *(const short8*)&tile[R * RCOLS + 8 * kb + 8 * whv];
#pragma unroll
            for (int ddg = 0; ddg < 4; ddg++) {
                const int rz = zi - 2 * ddg;
                if (rz >= 0 && rz < 8)
                    acc7[ddg] = __builtin_amdgcn_mfma_f32_16x16x32_bf16(
                        A7g[rz], B, acc7[ddg], 0, 0, 0);
            }
            if (has3) {
#pragma unroll
                for (int ddg = 0; ddg < 4; ddg++) {
                    const int rz3 = zi - 2 - 2 * ddg;
                    if (rz3 >= 0 && rz3 < 4)
                        acc3[ddg] = __builtin_amdgcn_mfma_f32_16x16x32_bf16(
                            A3g[rz3], B, acc3[ddg], 0, 0, 0);
                }
            }
        }
    }

    // ---- epilogue: C/D col n=q (h), row m=4p+r; residual x from LDS tile ----
#pragma unroll
    for (int ddg = 0; ddg < 4; ddg++) {
        const int d = d0 + zbase + 2 * ddg + khp;
        const int Rr = (zbase + 2 * ddg + khp + 3) * HR + (q + 3);
        uint2 u = *(const uint2*)&tile[Rr * RCOLS + 8 * whv + 4 * kb + 4];
        float xr[4];
        xr[0] = __builtin_bit_cast(float, u.x << 16);
        xr[1] = __builtin_bit_cast(float, u.x & 0xffff0000u);
        xr[2] = __builtin_bit_cast(float, u.y << 16);
        xr[3] = __builtin_bit_cast(float, u.y & 0xffff0000u);

        size_t off = ((size_t)(nb * Cc + c) * Dd + d) * (Hh * Ww)
                   + (size_t)(h0 + q) * Ww + w0 + 8 * whv + 4 * kb;
        float o[4];
#pragma unroll
        for (int r = 0; r < 4; r++) {
            float y7 = fmaxf(fmaf(acc7[ddg][r], iv7, bb7), 0.f);
            float y3 = fmaxf(fmaf(acc3[ddg][r], iv3, bb3), 0.f);
            float y1 = fmaxf(fmaf(xr[r], s1, bb1), 0.f);
            o[r] = fmaxf(xr[r] + y7 + y3 + y1, 0.f);
        }
        *(float4*)(out + off) = make_float4(o[0], o[1], o[2], o[3]);
    }
}

extern "C" void kernel_launch(void* const* d_in, const int* in_sizes, int n_in,
                              void* d_out, int out_size, void* d_ws, size_t ws_size,
                              hipStream_t stream) {
    const float* x  = (const float*)d_in[0];
    const float* w7 = (const float*)d_in[1];
    const float* w3 = (const float*)d_in[2];
    const float* w1 = (const float*)d_in[3];
    const float* g7 = (const float*)d_in[4];
    const float* b7 = (const float*)d_in[5];
    const float* m7 = (const float*)d_in[6];
    const float* v7 = (const float*)d_in[7];
    const float* g3 = (const float*)d_in[8];
    const float* b3 = (const float*)d_in[9];
    const float* m3 = (const float*)d_in[10];
    const float* v3 = (const float*)d_in[11];
    const float* g1 = (const float*)d_in[12];
    const float* b1 = (const float*)d_in[13];
    const float* m1 = (const float*)d_in[14];
    const float* v1 = (const float*)d_in[15];
    float* out = (float*)d_out;

    dim3 grid(8192);   // 1-D; kernel swizzles to (slab, tile) XCD-contiguously
    dim3 block(512);   // 8 waves: 4 d-groups x 2 w-halves sharing one LDS tile
    hipLaunchKernelGGL(replk_mfma, grid, block, 0, stream,
                       x, w7, w3, w1, g7, b7, m7, v7, g3, b3, m3, v3,
                       g1, b1, m1, v1, out);
}

// Round 23
// 241.785 us; speedup vs baseline: 3.4716x; 3.4716x over previous
//
#include <hip/hip_runtime.h>
#include <hip/hip_bf16.h>

#define Dd 64
#define Hh 128
#define Ww 128
#define Cc 32

// block tile: 32d x 16h x 16w outputs; 512 threads = 8 waves.
// wave = (dgrp 0..3) x (whv 0..1). r20 kernel + parity-split zi loops:
// live A-frags 8->4 (7^3) and 4->2 (3^3), -24 VGPR, zero added LDS work,
// so __launch_bounds__(512,6) (<=85 regs) fits WITHOUT the r22 spill
// -> 3 blocks/CU = 24 waves (r20 was reg-capped at 2 blocks / 42%).
#define BD 32
#define BH 16
#define BW 16
#define ZR (BD + 6)        // 38 staged z-planes
#define HR (BH + 6)        // 22 staged h-rows
#define NR (ZR * HR)       // 836 rows
#define RCOLS 24           // bf16 cols per row; col = w - w0 + 4 (left halo 4)
#define BLKROW 3
#define NBLK (NR * BLKROW) // 2508 16B blocks to stage

// A-table, b64 half-window entries: E(pl,s) = 4 taps [wt[s+j-7], j=0..3].
// fragment(pl,a) = (E(pl,a), E(pl,a+4)) — two ds_read_b64, +32B imm offset.
// 1016 entries x 8B = 8128 B. Total LDS 40128+8128 = 48256.
// Dead ends (measured): r12 global wtab = L2 storm; r13 rotation = worse
// banks; r15/16 incremental staging = serialized loads; r15 inline-asm MFMA
// = sched fence; r17 full unroll = spill; r21 BD=16 = +16% staging work;
// r22 (512,6) without reg reduction = acc spill (1.7GB writes).
#define E7 18
#define E3N 14
#define W3B (49 * E7)            // 882
#define ZE  (W3B + 9 * E3N)      // 1008 (zero region 1008..1015)
#define NEnt (ZE + 8)            // 1016

typedef __attribute__((ext_vector_type(8))) short short8;   // 8 bf16 (4 VGPR)
typedef __attribute__((ext_vector_type(4))) float floatx4;  // MFMA acc

static __device__ __forceinline__ unsigned short f2bf(float f) {
    unsigned u = __builtin_bit_cast(unsigned, f);
    u += 0x7fffu + ((u >> 16) & 1u);   // RNE
    return (unsigned short)(u >> 16);
}

static __device__ __forceinline__ unsigned pk2(float a, float b) {
    union { __hip_bfloat162 h; unsigned u; } cv;
    cv.h = __float22bfloat162_rn(make_float2(a, b));   // v_cvt_pk_bf16_f32
    return cv.u;
}

// fragment = two aligned b64 reads at entry idx and idx+4 (same base, +32B)
static __device__ __forceinline__ short8 ldfrag(const unsigned short* wt, int idx) {
    uint2 lo = *(const uint2*)&wt[idx * 4];
    uint2 hi = *(const uint2*)&wt[idx * 4 + 16];
    union { unsigned u[4]; short8 s; } cv;
    cv.u[0] = lo.x; cv.u[1] = lo.y; cv.u[2] = hi.x; cv.u[3] = hi.y;
    return cv.s;
}

__global__ __launch_bounds__(512, 6) void replk_mfma(
    const float* __restrict__ x,
    const float* __restrict__ w7, const float* __restrict__ w3, const float* __restrict__ w1,
    const float* __restrict__ g7, const float* __restrict__ b7, const float* __restrict__ m7, const float* __restrict__ v7,
    const float* __restrict__ g3, const float* __restrict__ b3, const float* __restrict__ m3, const float* __restrict__ v3,
    const float* __restrict__ g1, const float* __restrict__ b1, const float* __restrict__ m1, const float* __restrict__ v1,
    float* __restrict__ out)
{
    __shared__ __align__(16) unsigned short tile[NR * RCOLS];  // 40128 B
    __shared__ __align__(16) unsigned short wtab[NEnt * 4];    // 8128 B

    const int tid = threadIdx.x;

    // XCD-aware swizzle: 8192 blocks, 8 XCDs, 1024 contiguous per XCD.
    const unsigned lid = blockIdx.x;
    const unsigned nl = (lid & 7u) * 1024u + (lid >> 3);
    const int bx = nl & 127;
    const int slab = nl >> 7;
    const int c = slab & 31;
    const int nb = slab >> 5;
    const int w0 = (bx & 7) * BW;
    const int h0 = ((bx >> 3) & 7) * BH;
    const int d0 = (bx >> 6) * BD;

    const float* xc = x + (size_t)(nb * Cc + c) * (Dd * Hh * Ww);

    // ---- build A half-window table (b64 entries) ----
    for (int e = tid; e < NEnt; e += 512) {
        unsigned short h4[4];
#pragma unroll
        for (int j = 0; j < 4; j++) {
            float v = 0.f;
            if (e < W3B) {
                int pl = e / E7, s = e - pl * E7;
                int t = s + j - 7;
                if ((unsigned)t < 7u)
                    v = w7[c * 343 + (pl / 7) * 49 + (pl % 7) * 7 + t];
            } else if (e < ZE) {
                int e2 = e - W3B;
                int p3 = e2 / E3N, s = e2 - p3 * E3N;
                int t = s + j - 7;
                if ((unsigned)t < 3u)
                    v = w3[c * 27 + (p3 / 3) * 9 + (p3 % 3) * 3 + t];
            }
            h4[j] = f2bf(v);
        }
        uint2 pk;
        pk.x = (unsigned)h4[0] | ((unsigned)h4[1] << 16);
        pk.y = (unsigned)h4[2] | ((unsigned)h4[3] << 16);
        *(uint2*)&wtab[e * 4] = pk;
    }

    // ---- stage input tile fp32 -> bf16 (cvt_pk), division-based indices ----
    // (divisions keep the 5 iterations' addresses INDEPENDENT so all loads
    //  issue up front — incremental chains serialize them)
#pragma unroll
    for (int it = 0; it < 5; it++) {
        int s = tid + it * 512;
        if (s < NBLK) {
            int R = s / BLKROW, bl = s - R * BLKROW;
            int zi = R / HR, hr = R - zi * HR;
            int gz = d0 - 3 + zi, gh = h0 - 3 + hr, gw0 = w0 - 4 + bl * 8;
            float v[8];
#pragma unroll
            for (int j = 0; j < 8; j++) v[j] = 0.f;
            if ((unsigned)gz < (unsigned)Dd && (unsigned)gh < (unsigned)Hh) {
                const float* src = xc + ((size_t)gz * Hh + gh) * Ww + gw0;
                if (gw0 >= 0 && gw0 + 8 <= Ww) {
                    float4 a = *(const float4*)src;
                    float4 b = *(const float4*)(src + 4);
                    v[0] = a.x; v[1] = a.y; v[2] = a.z; v[3] = a.w;
                    v[4] = b.x; v[5] = b.y; v[6] = b.z; v[7] = b.w;
                } else {
#pragma unroll
                    for (int j = 0; j < 8; j++) {
                        int gw = gw0 + j;
                        if ((unsigned)gw < (unsigned)Ww) v[j] = src[j];
                    }
                }
            }
            uint4 pk;
            pk.x = pk2(v[0], v[1]);
            pk.y = pk2(v[2], v[3]);
            pk.z = pk2(v[4], v[5]);
            pk.w = pk2(v[6], v[7]);
            *(uint4*)&tile[R * RCOLS + bl * 8] = pk;
        }
    }

    // BN constants (wave-uniform)
    const float eps = 1e-5f;
    const float iv7 = g7[c] / sqrtf(v7[c] + eps);
    const float bb7 = b7[c] - m7[c] * iv7;
    const float iv3 = g3[c] / sqrtf(v3[c] + eps);
    const float bb3 = b3[c] - m3[c] * iv3;
    const float iv1 = g1[c] / sqrtf(v1[c] + eps);
    const float bb1 = b1[c] - m1[c] * iv1;
    const float s1 = w1[c] * iv1;

    __syncthreads();

    const int lane = tid & 63;
    const int wave = tid >> 6;        // 0..7
    const int whv = wave & 1;         // which 8-wide w half this wave owns
    const int dgrp = wave >> 1;       // which 8-d group
    const int q = lane & 15;          // m (A) / n (B,C,D)
    const int p = lane >> 4;
    const int khp = p >> 1;           // kh within pair
    const int kb  = p & 1;            // wc 16B-block
    const int ddl = q >> 3;           // d within M-pair (A side)
    const int mwq = q & 7;            // w within M (A side)
    const int zbase = dgrp * 8;       // wave's d-outputs [zbase, zbase+8)

    const int a7 = 8 * kb - mwq + 6;  // 7^3 window (valid [0,14))
    const int a3 = a7 - 2;            // 3^3 window (valid [0,10))

    floatx4 acc7[4], acc3[4];
#pragma unroll
    for (int i = 0; i < 4; i++) { acc7[i] = (floatx4)0.f; acc3[i] = (floatx4)0.f; }

    // ---- khg-outer loop with PARITY-SPLIT zi (r23): per parity sub-pass only
    //      4 A7 + 2 A3 fragments are live (was 8+4) — same loads, same MFMAs,
    //      same B-reads, just reordered accumulation ----
#pragma unroll 1
    for (int khg = 0; khg < 4; khg++) {
        const int kh = 2 * khg + khp;                       // 0..7 (7 = zero)
        const bool ok7 = ((unsigned)a7 < 14u) && (kh <= 6);
        const int cb7 = ok7 ? (kh * E7 + a7 - ddl * 126) : (int)ZE;
        const int st7 = ok7 ? 126 : 0;

        const bool has3 = (khg == 1) || (khg == 2);
        const int kh3 = 2 * (khg - 1) + khp;                // 0..3 (3 = zero)
        const bool ok3 = has3 && ((unsigned)a3 < 10u) && (kh3 <= 2);
        const int cb3 = ok3 ? (W3B + kh3 * E3N + a3 - ddl * 42) : (int)ZE;
        const int st3 = ok3 ? 42 : 0;

        // kh=7 lanes (khg=3, khp=1) have zero A: clamp their B row to kh=6's.
        const int rowadd = (khg == 3) ? 6 : (2 * khg + khp);

#pragma unroll 1
        for (int par = 0; par < 2; par++) {
            // live A-set for this parity: rz = 2k+par
            short8 A7h[4];
#pragma unroll
            for (int k = 0; k < 4; k++) {
                const int rz = 2 * k + par;
                int idx = cb7 + rz * st7;
                if (rz == 0) idx = (ddl == 0 && ok7) ? idx : (int)ZE;  // kd=-1 lanes
                if (rz == 7) idx = (ddl == 1 && ok7) ? idx : (int)ZE;  // kd=7 lanes
                A7h[k] = ldfrag(wtab, idx);
            }
            short8 A3h[2] = {};
            if (has3) {
#pragma unroll
                for (int k = 0; k < 2; k++) {
                    const int rz = 2 * k + par;
                    int idx = cb3 + rz * st3;
                    if (rz == 0) idx = (ddl == 0 && ok3) ? idx : (int)ZE;
                    if (rz == 3) idx = (ddl == 1 && ok3) ? idx : (int)ZE;
                    A3h[k] = ldfrag(wtab, idx);
                }
            }

#pragma unroll
            for (int zz = 0; zz < 7; zz++) {
                const int zi = 2 * zz + par;
                const int R = (zbase + zi) * HR + q + rowadd;
                short8 B = *(const short8*)&tile[R * RCOLS + 8 * kb + 8 * whv];
#pragma unroll
                for (int ddg = 0; ddg < 4; ddg++) {
                    const int k = zz - ddg;            // rz = 2k+par
                    if (k >= 0 && k < 4)
                        acc7[ddg] = __builtin_amdgcn_mfma_f32_16x16x32_bf16(
                            A7h[k], B, acc7[ddg], 0, 0, 0);
                }
                if (has3) {
#pragma unroll
                    for (int ddg = 0; ddg < 4; ddg++) {
                        const int k3 = zz - 1 - ddg;   // rz3 = 2k3+par
                        if (k3 >= 0 && k3 < 2)
                            acc3[ddg] = __builtin_amdgcn_mfma_f32_16x16x32_bf16(
                                A3h[k3], B, acc3[ddg], 0, 0, 0);
                    }
                }
            }
        }
    }

    // ---- epilogue: C/D col n=q (h), row m=4p+r; residual x from LDS tile ----
#pragma unroll
    for (int ddg = 0; ddg < 4; ddg++) {
        const int d = d0 + zbase + 2 * ddg + khp;
        const int Rr = (zbase + 2 * ddg + khp + 3) * HR + (q + 3);
        uint2 u = *(const uint2*)&tile[Rr * RCOLS + 8 * whv + 4 * kb + 4];
        float xr[4];
        xr[0] = __builtin_bit_cast(float, u.x << 16);
        xr[1] = __builtin_bit_cast(float, u.x & 0xffff0000u);
        xr[2] = __builtin_bit_cast(float, u.y << 16);
        xr[3] = __builtin_bit_cast(float, u.y & 0xffff0000u);

        size_t off = ((size_t)(nb * Cc + c) * Dd + d) * (Hh * Ww)
                   + (size_t)(h0 + q) * Ww + w0 + 8 * whv + 4 * kb;
        float o[4];
#pragma unroll
        for (int r = 0; r < 4; r++) {
            float y7 = fmaxf(fmaf(acc7[ddg][r], iv7, bb7), 0.f);
            float y3 = fmaxf(fmaf(acc3[ddg][r], iv3, bb3), 0.f);
            float y1 = fmaxf(fmaf(xr[r], s1, bb1), 0.f);
            o[r] = fmaxf(xr[r] + y7 + y3 + y1, 0.f);
        }
        *(float4*)(out + off) = make_float4(o[0], o[1], o[2], o[3]);
    }
}

extern "C" void kernel_launch(void* const* d_in, const int* in_sizes, int n_in,
                              void* d_out, int out_size, void* d_ws, size_t ws_size,
                              hipStream_t stream) {
    const float* x  = (const float*)d_in[0];
    const float* w7 = (const float*)d_in[1];
    const float* w3 = (const float*)d_in[2];
    const float* w1 = (const float*)d_in[3];
    const float* g7 = (const float*)d_in[4];
    const float* b7 = (const float*)d_in[5];
    const float* m7 = (const float*)d_in[6];
    const float* v7 = (const float*)d_in[7];
    const float* g3 = (const float*)d_in[8];
    const float* b3 = (const float*)d_in[9];
    const float* m3 = (const float*)d_in[10];
    const float* v3 = (const float*)d_in[11];
    const float* g1 = (const float*)d_in[12];
    const float* b1 = (const float*)d_in[13];
    const float* m1 = (const float*)d_in[14];
    const float* v1 = (const float*)d_in[15];
    float* out = (float*)d_out;

    dim3 grid(8192);   // 1-D; kernel swizzles to (slab, tile) XCD-contiguously
    dim3 block(512);   // 8 waves: 4 d-groups x 2 w-halves sharing one LDS tile
    hipLaunchKernelGGL(replk_mfma, grid, block, 0, stream,
                       x, w7, w3, w1, g7, b7, m7, v7, g3, b3, m3, v3,
                       g1, b1, m1, v1, out);
}